// Round 7
// baseline (2707.492 us; speedup 1.0000x reference)
//
#include <hip/hip_runtime.h>

#define HH   51
#define H4   204
#define TSEQ 2048
#define FUT  64
#define TT   (TSEQ + FUT)   // 2112
#define RPB  16             // batch rows per block (2 blocks/CU)
#define NTH  1024           // 16 waves: 13 compute + emit + prefetch + 1 idle (proven 2-block packing)
#define HSTR 72             // halfs per hbuf row (144 B stride)

typedef _Float16 h8 __attribute__((ext_vector_type(8)));
typedef float    f4 __attribute__((ext_vector_type(4)));

#define LOG2E 1.44269504f
#define MFMA(a, b, c) __builtin_amdgcn_mfma_f32_16x16x32_f16(a, b, c, 0, 0, 0)

// P1 (recurrence, CRITICAL CHAIN) activation: two independent rcps = shortest
// dependency chain (R2-proven numerics). Pre-scaled preacts:
//   g[0]=-L*zi, g[1]=-L*zf, g[2]=-2L*zg, g[3]=-L*zo  (L = log2 e)
__device__ __forceinline__ void act_p1(const f4 g, float cin, float* cout, float* hout) {
    const float ei = __builtin_amdgcn_exp2f(g[0]);
    const float ef = __builtin_amdgcn_exp2f(g[1]);
    const float eg = __builtin_amdgcn_exp2f(g[2]);
    const float eo = __builtin_amdgcn_exp2f(g[3]);
    const float A = 1.0f + ei, B = 1.0f + ef, G = 1.0f + eg, C = 1.0f + eo;
    const float rAB = __builtin_amdgcn_rcpf(A * B);
    const float rGC = __builtin_amdgcn_rcpf(G * C);
    const float ig = rAB * B;                                 // sigmoid(zi)
    const float fg = rAB * A;                                 // sigmoid(zf)
    const float og = rGC * G;                                 // sigmoid(zo)
    const float tg = __builtin_fmaf(2.0f, rGC * C, -1.0f);    // tanh(zg)
    const float c2 = __builtin_fmaf(fg, cin, ig * tg);
    const float ec = __builtin_amdgcn_exp2f(-2.0f * LOG2E * c2);
    const float th = __builtin_fmaf(2.0f, __builtin_amdgcn_rcpf(1.0f + ec), -1.0f);
    *cout = c2;
    *hout = og * th;
}

// P2 (emit, OFF the chain) activation: single shared rcp = fewest issue slots.
__device__ __forceinline__ void act6(const f4 g, float cin, float* cout, float* hout) {
    const float ei = __builtin_amdgcn_exp2f(g[0]);
    const float ef = __builtin_amdgcn_exp2f(g[1]);
    const float eg = __builtin_amdgcn_exp2f(g[2]);
    const float eo = __builtin_amdgcn_exp2f(g[3]);
    const float A = 1.0f + ei, B = 1.0f + ef, G = 1.0f + eg, C = 1.0f + eo;
    const float AB = A * B, GC = G * C;
    const float r  = __builtin_amdgcn_rcpf(AB * GC);
    const float t1 = A * GC;                      // -> f = r*t1
    const float t4 = (B * C) * (2.0f - G);        // -> i*tanh(g) = r*t4
    const float c2 = r * __builtin_fmaf(t1, cin, t4);
    const float og = r * (AB * G);                // sigmoid(zo)
    const float ec = __builtin_amdgcn_exp2f(-2.0f * LOG2E * c2);
    const float th = __builtin_fmaf(2.0f, __builtin_amdgcn_rcpf(1.0f + ec), -1.0f);
    *cout = c2;
    *hout = og * th;
}

// Merged iteration i (parity P = i&1): P2(i-1) + P1(i), ONE barrier per step.
// Chain-directed schedule:
//   - 4 MFMAs with INDEPENDENT zero-C accumulators (no mfma->mfma serial dep),
//     P1's pair issued first; recombine with a vector add.
//   - act_p1 + h1 ds_write run FIRST (the value the next barrier waits on),
//     act6 + part write fill the remaining time before the barrier.
#define MERGED_BODY(P, EMIT_IDX, DO_EMIT, XI)                                      \
    do {                                                                           \
        if (is_comp) {                                                             \
            const h8 b0 = *(const h8*)&hbuf[P][nl][quad * 8];                      \
            const h8 b1 = *(const h8*)&hbuf[P][nl][32 + quad * 8];                 \
            const f4 zz = {0.f, 0.f, 0.f, 0.f};                                    \
            const f4 G1a = MFMA(W1[0], b0, zz);                                    \
            const f4 G1b = MFMA(W1[1], b1, zz);                                    \
            const f4 G2a = MFMA(W2[0], b0, zz);                                    \
            const f4 G2b = MFMA(W2[1], b1, zz);                                    \
            const f4 G1 = G1a + G1b;                                               \
            const float c1o = c1;                                                  \
            float hv;                                                              \
            act_p1(G1, c1o, &c1, &hv);           /* P1(i): updates c1 */           \
            if (kh < HH) hbuf[(P) ^ 1][nl][1 + kh] = (_Float16)hv;                 \
            const f4 G2 = G2a + G2b;                                               \
            float c2v, h2v;                                                        \
            act6(G2, c1o, &c2v, &h2v);           /* P2(i-1): uses pre-update c1 */ \
            part[(P) ^ 1][cw][quad][nl] = h2v * wo;                                \
        } else if (w == we) {                                                      \
            if ((DO_EMIT) && lane < RPB) {                                         \
                float s0 = bo, s1 = 0.f, s2 = 0.f, s3 = 0.f;                       \
                _Pragma("unroll")                                                  \
                for (int j = 0; j < 13; ++j) {                                     \
                    s0 += part[P][j][0][lane];                                     \
                    s1 += part[P][j][1][lane];                                     \
                    s2 += part[P][j][2][lane];                                     \
                    s3 += part[P][j][3][lane];                                     \
                }                                                                  \
                out[(size_t)(rb + lane) * TT + (EMIT_IDX)] = (s0 + s1) + (s2 + s3);\
            }                                                                      \
        } else if (w == wp && lane < RPB) {                                        \
            if ((XI) + 1 < TSEQ) hbuf[(P) ^ 1][lane][0] = (_Float16)xnext;         \
            if ((XI) + 2 < TSEQ) xnext = x[(size_t)(rb + lane) * TSEQ + (XI) + 2]; \
        }                                                                          \
        __syncthreads();                                                           \
    } while (0)

__global__ __launch_bounds__(NTH, 8)
void lstm_kernel(const float* __restrict__ x,
                 const float* __restrict__ Wih1, const float* __restrict__ Whh1,
                 const float* __restrict__ bih1, const float* __restrict__ bhh1,
                 const float* __restrict__ Wih2, const float* __restrict__ Whh2,
                 const float* __restrict__ bih2, const float* __restrict__ bhh2,
                 const float* __restrict__ Wout, const float* __restrict__ bout,
                 float* __restrict__ out)
{
    // double-buffered B-operand: [buf][row][k]; k=0: x_t, 1..51: h1, 52,53: const 1 (bias hi/lo)
    __shared__ _Float16 hbuf[2][RPB][HSTR];
    // per-(tile,quad) partials of wout.h2, double-buffered: [buf][tile][quad][row]
    __shared__ float part[2][13][4][17];
    __shared__ float wouts[64];

    const int tid  = threadIdx.x;
    const int lane = tid & 63;
    const int w    = tid >> 6;        // physical wave id (SIMD = w & 3)
    const int quad = lane >> 4;       // 0..3
    const int nl   = lane & 15;       // batch row (B-operand n / C-D col)
    const int rb   = blockIdx.x * RPB;

    // Role rotation: 13 compute waves split 4-3-3-3 over SIMDs; co-resident
    // blocks (b, b+256) use shifts 0 / 3 -> combined 7/6/6/7 per SIMD.
    const int  rot     = (blockIdx.x >> 8) & 1;
    const int  cw      = w - (rot ? 3 : 0);     // compute tile id if in [0,13)
    const bool is_comp = (cw >= 0) && (cw < 13);
    const int  we      = rot ? 0 : 13;          // emit wave
    const int  wp      = rot ? 1 : 14;          // x-prefetch wave

    // ---------------- one-time init ----------------
    if (tid < 64) wouts[tid] = (tid < HH) ? Wout[tid] : 0.0f;
    for (int i = tid; i < 2 * RPB * HSTR; i += NTH) (&hbuf[0][0][0])[i] = (_Float16)0.0f;
    __syncthreads();
    if (tid < RPB) {
        hbuf[0][tid][0]  = (_Float16)x[(size_t)(rb + tid) * TSEQ];
        hbuf[0][tid][52] = (_Float16)1.0f;  hbuf[0][tid][53] = (_Float16)1.0f;
        hbuf[1][tid][52] = (_Float16)1.0f;  hbuf[1][tid][53] = (_Float16)1.0f;
    }
    const float bo = bout[0];

    // ---------------- weight A-fragments in registers (once) ----------------
    // compute wave cw owns gate m-tile cw: rows j' = 16cw..16cw+15 (j' = 4k+q interleave)
    // Gate rows pre-scaled so MFMA emits exp2-ready args: i,f,o by -log2e, g by -2 log2e.
    h8 W1[2], W2[2];
    if (is_comp) {
        const int jp = 16 * cw + nl;
        const int kk = jp >> 2, q = jp & 3;
        const bool valid = (jp < H4);
        const int jrow = q * HH + kk;        // original gate row
        const float sc = (q == 2) ? (-2.0f * LOG2E) : (-LOG2E);
        float b1 = 0.0f, b2 = 0.0f;
        if (valid) { b1 = sc * (bih1[jrow] + bhh1[jrow]); b2 = sc * (bih2[jrow] + bhh2[jrow]); }
        const _Float16 b1h = (_Float16)b1, b2h = (_Float16)b2;
        const _Float16 b1l = (_Float16)(b1 - (float)b1h), b2l = (_Float16)(b2 - (float)b2h);
        #pragma unroll
        for (int s = 0; s < 2; ++s) {
            h8 w1v, w2v;
            #pragma unroll
            for (int j = 0; j < 8; ++j) {
                const int k = s * 32 + quad * 8 + j;
                _Float16 a1 = (_Float16)0.0f, a2 = (_Float16)0.0f;
                if (valid) {
                    if (k == 0) {
                        a1 = (_Float16)(sc * Wih1[jrow]);
                    } else if (k <= HH) {
                        const int o = jrow * HH + (k - 1);
                        a1 = (_Float16)(sc * Whh1[o]);
                        a2 = (_Float16)(sc * (Wih2[o] + Whh2[o]));
                    } else if (k == 52) { a1 = b1h; a2 = b2h; }
                    else if (k == 53)   { a1 = b1l; a2 = b2l; }
                }
                w1v[j] = a1;
                w2v[j] = a2;
            }
            W1[s] = w1v;
            W2[s] = w2v;
        }
    }

    // x register pipeline: at merged iteration i, write x(i+1), then load x(i+2)
    float xnext = 0.0f;
    if (w == wp && lane < RPB) xnext = x[(size_t)(rb + lane) * TSEQ + 1];

    const int kh = 4 * cw + quad;     // hidden unit owned by this lane (if is_comp)
    float c1 = 0.0f;
    __syncthreads();
    const float wo = is_comp ? wouts[kh] : 0.0f;

    // ---------------- peel i = 0 : P1(0) only ----------------
    if (is_comp) {
        const h8 b0 = *(const h8*)&hbuf[0][nl][quad * 8];
        const h8 b1 = *(const h8*)&hbuf[0][nl][32 + quad * 8];
        const f4 zz = {0.f, 0.f, 0.f, 0.f};
        const f4 G1a = MFMA(W1[0], b0, zz);
        const f4 G1b = MFMA(W1[1], b1, zz);
        const f4 G1 = G1a + G1b;
        float hv;
        act_p1(G1, c1, &c1, &hv);
        if (kh < HH) hbuf[1][nl][1 + kh] = (_Float16)hv;
    } else if (w == wp && lane < RPB) {
        hbuf[1][lane][0] = (_Float16)xnext;               // x(1)
        xnext = x[(size_t)(rb + lane) * TSEQ + 2];        // x(2)
    }
    __syncthreads();

    // ---------------- peel i = 1 : P2(0) + P1(1), nothing to emit yet ----------------
    MERGED_BODY(1, 0, false, 1);

    // ---------------- main: merged iterations i = 2 .. TSEQ-1, unrolled x2 ----------------
    for (int i = 2; i < TSEQ; i += 2) {
        MERGED_BODY(0, i - 2, true, i);
        MERGED_BODY(1, i - 1, true, i + 1);
    }
    // state: P1 done through 2047, P2 done through 2046,
    // out emitted through 2045; part[0] holds P2(2046).

    // ---------------- FUT tail: t = TSEQ-1 .. TT-1, explicit 3-phase ----------------
    for (int t = TSEQ - 1; t < TT; ++t) {
        const int pb = (t + 1) & 1;   // buffer holding h1 post-step-t (+ feedback x slot)
        if (is_comp) {
            // P2(t)
            const h8 b0 = *(const h8*)&hbuf[pb][nl][quad * 8];
            const h8 b1 = *(const h8*)&hbuf[pb][nl][32 + quad * 8];
            const f4 zz = {0.f, 0.f, 0.f, 0.f};
            const f4 G2a = MFMA(W2[0], b0, zz);
            const f4 G2b = MFMA(W2[1], b1, zz);
            const f4 G2 = G2a + G2b;
            float c2v, h2v;
            act6(G2, c1, &c2v, &h2v);
            part[t & 1][cw][quad][nl] = h2v * wo;
        } else if (w == we && t == TSEQ - 1 && lane < RPB) {
            // emit out(TSEQ-2) from part[0] (written during the last main iter)
            float s0 = bo, s1 = 0.f, s2 = 0.f, s3 = 0.f;
            #pragma unroll
            for (int j = 0; j < 13; ++j) {
                s0 += part[0][j][0][lane];
                s1 += part[0][j][1][lane];
                s2 += part[0][j][2][lane];
                s3 += part[0][j][3][lane];
            }
            out[(size_t)(rb + lane) * TT + (TSEQ - 2)] = (s0 + s1) + (s2 + s3);
        }
        __syncthreads();
        if (w == we && lane < RPB) {
            float s0 = bo, s1 = 0.f, s2 = 0.f, s3 = 0.f;
            #pragma unroll
            for (int j = 0; j < 13; ++j) {
                s0 += part[t & 1][j][0][lane];
                s1 += part[t & 1][j][1][lane];
                s2 += part[t & 1][j][2][lane];
                s3 += part[t & 1][j][3][lane];
            }
            const float s = (s0 + s1) + (s2 + s3);
            out[(size_t)(rb + lane) * TT + t] = s;
            if (t + 1 < TT) hbuf[pb][lane][0] = (_Float16)s;   // autoregressive x(t+1)
        }
        __syncthreads();
        if (t + 1 < TT) {
            if (is_comp) {
                // P1(t+1): reads hbuf[pb] (h1 post-t + feedback x), writes h1 post-(t+1)
                const h8 b0 = *(const h8*)&hbuf[pb][nl][quad * 8];
                const h8 b1 = *(const h8*)&hbuf[pb][nl][32 + quad * 8];
                const f4 zz = {0.f, 0.f, 0.f, 0.f};
                const f4 G1a = MFMA(W1[0], b0, zz);
                const f4 G1b = MFMA(W1[1], b1, zz);
                const f4 G1 = G1a + G1b;
                float hv;
                act_p1(G1, c1, &c1, &hv);
                if (kh < HH) hbuf[pb ^ 1][nl][1 + kh] = (_Float16)hv;
            }
            __syncthreads();
        }
    }
}

extern "C" void kernel_launch(void* const* d_in, const int* in_sizes, int n_in,
                              void* d_out, int out_size, void* d_ws, size_t ws_size,
                              hipStream_t stream) {
    (void)in_sizes; (void)n_in; (void)d_ws; (void)ws_size; (void)out_size;
    const float* x    = (const float*)d_in[0];
    const float* Wih1 = (const float*)d_in[1];
    const float* Whh1 = (const float*)d_in[2];
    const float* bih1 = (const float*)d_in[3];
    const float* bhh1 = (const float*)d_in[4];
    const float* Wih2 = (const float*)d_in[5];
    const float* Whh2 = (const float*)d_in[6];
    const float* bih2 = (const float*)d_in[7];
    const float* bhh2 = (const float*)d_in[8];
    const float* Wout = (const float*)d_in[9];
    const float* bout = (const float*)d_in[10];
    float* outp = (float*)d_out;

    dim3 grid(8192 / RPB);   // 512 blocks, 2 per CU
    dim3 block(NTH);
    hipLaunchKernelGGL(lstm_kernel, grid, block, 0, stream,
                       x, Wih1, Whh1, bih1, bhh1, Wih2, Whh2, bih2, bhh2,
                       Wout, bout, outp);
}

// Round 8
// 2603.292 us; speedup vs baseline: 1.0400x; 1.0400x over previous
//
#include <hip/hip_runtime.h>

#define HH   51
#define H4   204
#define TSEQ 2048
#define FUT  64
#define TT   (TSEQ + FUT)   // 2112
#define RPB  16             // batch rows per block
#define NTH  256            // 4 waves/block: tiles split 4/3/3/3, emit folded into a 3-tile wave
#define HSTR 72             // halfs per hbuf row (144 B stride)

typedef _Float16 h8 __attribute__((ext_vector_type(8)));
typedef float    f4 __attribute__((ext_vector_type(4)));

#define LOG2E 1.44269504f
#define MFMA(a, b, c) __builtin_amdgcn_mfma_f32_16x16x32_f16(a, b, c, 0, 0, 0)

// LSTM-cell nonlinearity, 7 transcendentals (R6-proven best).
// Pre-scaled gate preacts: g[0]=-L*zi, g[1]=-L*zf, g[2]=-2L*zg, g[3]=-L*zo.
// ONE shared rcp recovers all gates; sigma(i)*tanh(g) computed as a product.
__device__ __forceinline__ void act6(const f4 g, float cin, float* cout, float* hout) {
    const float ei = __builtin_amdgcn_exp2f(g[0]);
    const float ef = __builtin_amdgcn_exp2f(g[1]);
    const float eg = __builtin_amdgcn_exp2f(g[2]);
    const float eo = __builtin_amdgcn_exp2f(g[3]);
    const float A = 1.0f + ei, B = 1.0f + ef, G = 1.0f + eg, C = 1.0f + eo;
    const float AB = A * B, GC = G * C;
    const float r  = __builtin_amdgcn_rcpf(AB * GC);
    const float t1 = A * GC;                      // -> f = r*t1
    const float t4 = (B * C) * (2.0f - G);        // -> i*tanh(g) = r*t4
    const float c2 = r * __builtin_fmaf(t1, cin, t4);
    const float og = r * (AB * G);                // sigmoid(zo)
    const float ec = __builtin_amdgcn_exp2f(-2.0f * LOG2E * c2);
    const float th = __builtin_fmaf(2.0f, __builtin_amdgcn_rcpf(1.0f + ec), -1.0f);
    *cout = c2;
    *hout = og * th;
}

// P1 recurrence over this wave's NT tiles: updates c1[], writes h1 -> hn.
template<int NT>
__device__ __forceinline__ void do_p1(const h8 (&W1)[4][2], float (&c1)[4],
                                      const h8 b0, const h8 b1,
                                      _Float16 (*hn)[HSTR], int t0, int quad, int nl)
{
    const f4 zz = {0.f, 0.f, 0.f, 0.f};
    #pragma unroll
    for (int tt = 0; tt < NT; ++tt) {
        const f4 G1 = MFMA(W1[tt][1], b1, MFMA(W1[tt][0], b0, zz));
        float hv;
        act6(G1, c1[tt], &c1[tt], &hv);
        const int kh = 4 * (t0 + tt) + quad;
        if (kh < HH) hn[nl][1 + kh] = (_Float16)hv;
    }
}

// P2 emit over this wave's NT tiles: returns lane-local partial sum wo.h2
// (c1[] NOT updated - P2 uses the current c1 per reference emit()).
template<int NT>
__device__ __forceinline__ float do_p2(const h8 (&W2)[4][2], const float (&c1)[4],
                                       const float (&wo)[4], const h8 b0, const h8 b1)
{
    const f4 zz = {0.f, 0.f, 0.f, 0.f};
    float p = 0.f;
    #pragma unroll
    for (int tt = 0; tt < NT; ++tt) {
        const f4 G2 = MFMA(W2[tt][1], b1, MFMA(W2[tt][0], b0, zz));
        float c2v, h2v;
        act6(G2, c1[tt], &c2v, &h2v);
        p = __builtin_fmaf(h2v, wo[tt], p);
    }
    return p;
}

// Merged iteration i (parity P=i&1): P2(i-1) + P1(i), ONE barrier per step.
// Each wave: 1 pair of b128 reads feeds all its tiles x both cells; per-lane
// local wo.h2 accumulation -> ONE part write. Emitter wave (role 3): x
// prefetch issued early (hides L2 latency), then out(i-2) from part[P].
#define MERGED(P, EIDX, DOE, XI)                                              \
    do {                                                                      \
        const h8 b0 = *(const h8*)&hbuf[P][nl][quad * 8];                     \
        const h8 b1 = *(const h8*)&hbuf[P][nl][32 + quad * 8];                \
        float p;                                                              \
        if (four) {                                                           \
            p = do_p2<4>(W2, c1_t, wo_t, b0, b1);                             \
            do_p1<4>(W1, c1_t, b0, b1, hbuf[(P) ^ 1], t0, quad, nl);          \
        } else {                                                              \
            p = do_p2<3>(W2, c1_t, wo_t, b0, b1);                             \
            do_p1<3>(W1, c1_t, b0, b1, hbuf[(P) ^ 1], t0, quad, nl);          \
        }                                                                     \
        part[(P) ^ 1][quad][nl][w] = p;                                       \
        if (is_em) {                                                          \
            if (quad == 0) {                                                  \
                if ((XI) + 1 < TSEQ) hbuf[(P) ^ 1][nl][0] = (_Float16)xnext;  \
                if ((XI) + 2 < TSEQ)                                          \
                    xnext = x[(size_t)(rb + nl) * TSEQ + (XI) + 2];           \
            }                                                                 \
            if (DOE) {                                                        \
                const f4 v = *(const f4*)&part[P][quad][nl][0];               \
                float s = (v[0] + v[1]) + (v[2] + v[3]);                      \
                s += __shfl_xor(s, 16, 64);                                   \
                s += __shfl_xor(s, 32, 64);                                   \
                if (quad == 0) out[(size_t)(rb + nl) * TT + (EIDX)] = s + bo; \
            }                                                                 \
        }                                                                     \
        __syncthreads();                                                      \
    } while (0)

__global__ __launch_bounds__(NTH, 2)   // 2 blocks/CU -> 8 waves/CU, 2/SIMD
void lstm_kernel(const float* __restrict__ x,
                 const float* __restrict__ Wih1, const float* __restrict__ Whh1,
                 const float* __restrict__ bih1, const float* __restrict__ bhh1,
                 const float* __restrict__ Wih2, const float* __restrict__ Whh2,
                 const float* __restrict__ bih2, const float* __restrict__ bhh2,
                 const float* __restrict__ Wout, const float* __restrict__ bout,
                 float* __restrict__ out)
{
    // double-buffered B-operand: [buf][row][k]; k=0: x_t, 1..51: h1, 52,53: 1 (bias hi/lo)
    __shared__ _Float16 hbuf[2][RPB][HSTR];
    // per-wave lane-local partials of wout.h2: [buf][quad][row][wave] (b128-readable)
    __shared__ float part[2][4][RPB][4];

    const int tid  = threadIdx.x;
    const int lane = tid & 63;
    const int w    = tid >> 6;        // wave id 0..3 (SIMD = w)
    const int quad = lane >> 4;
    const int nl   = lane & 15;       // batch row
    const int rb   = blockIdx.x * RPB;

    // Tile roles: 13 m-tiles split 4/3/3/3. Heavy role (0) rotates across
    // SIMDs per block so co-resident blocks balance; role 3 also does
    // emit + x-prefetch (3 tiles -> has slack vs the 4-tile wave).
    const int  rot   = (blockIdx.x + (blockIdx.x >> 8)) & 3;
    const int  role  = (w + rot) & 3;
    const int  t0    = (role == 0) ? 0 : (role == 1) ? 4 : (role == 2) ? 7 : 10;
    const bool four  = (role == 0);
    const bool is_em = (role == 3);

    // ---------------- one-time init ----------------
    for (int i = tid; i < 2 * RPB * HSTR; i += NTH) (&hbuf[0][0][0])[i] = (_Float16)0.0f;
    __syncthreads();
    if (tid < RPB) {
        hbuf[0][tid][0]  = (_Float16)x[(size_t)(rb + tid) * TSEQ];
        hbuf[0][tid][52] = (_Float16)1.0f;  hbuf[0][tid][53] = (_Float16)1.0f;
        hbuf[1][tid][52] = (_Float16)1.0f;  hbuf[1][tid][53] = (_Float16)1.0f;
    }
    const float bo = bout[0];

    // ---------------- weight A-fragments (per-tile, in registers) ----------------
    // m-tile t: gate rows j' = 16t..16t+15 (j' = 4k+q interleave); lane's hidden
    // unit kh = 4t+quad. Rows pre-scaled: i,f,o by -log2e, g by -2log2e.
    h8 W1[4][2], W2[4][2];
    float wo_t[4], c1_t[4];
    h8 hz;
    #pragma unroll
    for (int j = 0; j < 8; ++j) hz[j] = (_Float16)0.0f;
    const int ntl = four ? 4 : 3;
    #pragma unroll
    for (int tt = 0; tt < 4; ++tt) {
        c1_t[tt] = 0.0f; wo_t[tt] = 0.0f;
        W1[tt][0] = hz; W1[tt][1] = hz; W2[tt][0] = hz; W2[tt][1] = hz;
        if (tt < ntl) {
            const int t = t0 + tt;
            const int jp = 16 * t + nl;
            const int kk = jp >> 2, q = jp & 3;
            const bool valid = (jp < H4);
            const int jrow = q * HH + kk;
            const float sc = (q == 2) ? (-2.0f * LOG2E) : (-LOG2E);
            float b1v = 0.0f, b2v = 0.0f;
            if (valid) { b1v = sc * (bih1[jrow] + bhh1[jrow]); b2v = sc * (bih2[jrow] + bhh2[jrow]); }
            const _Float16 b1h = (_Float16)b1v, b2h = (_Float16)b2v;
            const _Float16 b1l = (_Float16)(b1v - (float)b1h), b2l = (_Float16)(b2v - (float)b2h);
            #pragma unroll
            for (int s = 0; s < 2; ++s) {
                h8 w1v = hz, w2v = hz;
                #pragma unroll
                for (int j = 0; j < 8; ++j) {
                    const int k = s * 32 + quad * 8 + j;
                    _Float16 a1 = (_Float16)0.0f, a2 = (_Float16)0.0f;
                    if (valid) {
                        if (k == 0) {
                            a1 = (_Float16)(sc * Wih1[jrow]);
                        } else if (k <= HH) {
                            const int o = jrow * HH + (k - 1);
                            a1 = (_Float16)(sc * Whh1[o]);
                            a2 = (_Float16)(sc * (Wih2[o] + Whh2[o]));
                        } else if (k == 52) { a1 = b1h; a2 = b2h; }
                        else if (k == 53)   { a1 = b1l; a2 = b2l; }
                    }
                    w1v[j] = a1;
                    w2v[j] = a2;
                }
                W1[tt][s] = w1v;
                W2[tt][s] = w2v;
            }
            const int kh = 4 * t + quad;
            wo_t[tt] = (kh < HH) ? Wout[kh] : 0.0f;
        }
    }

    // x register pipeline (emitter wave, quad-0 lanes)
    float xnext = 0.0f;
    if (is_em && quad == 0) xnext = x[(size_t)(rb + nl) * TSEQ + 1];
    __syncthreads();

    // ---------------- peel i = 0 : P1(0) only ----------------
    {
        const h8 b0 = *(const h8*)&hbuf[0][nl][quad * 8];
        const h8 b1 = *(const h8*)&hbuf[0][nl][32 + quad * 8];
        if (four) do_p1<4>(W1, c1_t, b0, b1, hbuf[1], t0, quad, nl);
        else      do_p1<3>(W1, c1_t, b0, b1, hbuf[1], t0, quad, nl);
        if (is_em && quad == 0) {
            hbuf[1][nl][0] = (_Float16)xnext;              // x(1)
            xnext = x[(size_t)(rb + nl) * TSEQ + 2];       // x(2)
        }
        __syncthreads();
    }

    // ---------------- peel i = 1 : P2(0) + P1(1), nothing to emit ----------------
    MERGED(1, 0, false, 1);

    // ---------------- main: i = 2 .. TSEQ-1, unrolled x2 ----------------
    for (int i = 2; i < TSEQ; i += 2) {
        MERGED(0, i - 2, true, i);
        MERGED(1, i - 1, true, i + 1);
    }
    // state: P1 done through 2047 (h1 in hbuf[0]); part[0] = P2(2046);
    // out emitted through 2045.

    // ---------------- FUT tail: t = TSEQ-1 .. TT-1, explicit 3-phase ----------------
    for (int t = TSEQ - 1; t < TT; ++t) {
        const int pb = (t + 1) & 1;   // buffer holding h1 post-step-t (+ feedback x)
        {
            const h8 b0 = *(const h8*)&hbuf[pb][nl][quad * 8];
            const h8 b1 = *(const h8*)&hbuf[pb][nl][32 + quad * 8];
            float p;
            if (four) p = do_p2<4>(W2, c1_t, wo_t, b0, b1);
            else      p = do_p2<3>(W2, c1_t, wo_t, b0, b1);
            part[t & 1][quad][nl][w] = p;
        }
        if (is_em && t == TSEQ - 1) {
            // emit out(TSEQ-2) from part[0] (written during the last main iter)
            const f4 v = *(const f4*)&part[0][quad][nl][0];
            float s = (v[0] + v[1]) + (v[2] + v[3]);
            s += __shfl_xor(s, 16, 64);
            s += __shfl_xor(s, 32, 64);
            if (quad == 0) out[(size_t)(rb + nl) * TT + (TSEQ - 2)] = s + bo;
        }
        __syncthreads();
        if (is_em) {
            const f4 v = *(const f4*)&part[t & 1][quad][nl][0];
            float s = (v[0] + v[1]) + (v[2] + v[3]);
            s += __shfl_xor(s, 16, 64);
            s += __shfl_xor(s, 32, 64);
            s += bo;
            if (quad == 0) {
                out[(size_t)(rb + nl) * TT + t] = s;
                if (t + 1 < TT) hbuf[pb][nl][0] = (_Float16)s;   // autoregressive x(t+1)
            }
        }
        __syncthreads();
        if (t + 1 < TT) {
            const h8 b0 = *(const h8*)&hbuf[pb][nl][quad * 8];
            const h8 b1 = *(const h8*)&hbuf[pb][nl][32 + quad * 8];
            if (four) do_p1<4>(W1, c1_t, b0, b1, hbuf[pb ^ 1], t0, quad, nl);
            else      do_p1<3>(W1, c1_t, b0, b1, hbuf[pb ^ 1], t0, quad, nl);
            __syncthreads();
        }
    }
}

extern "C" void kernel_launch(void* const* d_in, const int* in_sizes, int n_in,
                              void* d_out, int out_size, void* d_ws, size_t ws_size,
                              hipStream_t stream) {
    (void)in_sizes; (void)n_in; (void)d_ws; (void)ws_size; (void)out_size;
    const float* x    = (const float*)d_in[0];
    const float* Wih1 = (const float*)d_in[1];
    const float* Whh1 = (const float*)d_in[2];
    const float* bih1 = (const float*)d_in[3];
    const float* bhh1 = (const float*)d_in[4];
    const float* Wih2 = (const float*)d_in[5];
    const float* Whh2 = (const float*)d_in[6];
    const float* bih2 = (const float*)d_in[7];
    const float* bhh2 = (const float*)d_in[8];
    const float* Wout = (const float*)d_in[9];
    const float* bout = (const float*)d_in[10];
    float* outp = (float*)d_out;

    dim3 grid(8192 / RPB);   // 512 blocks x 256 thr, 2 blocks/CU
    dim3 block(NTH);
    hipLaunchKernelGGL(lstm_kernel, grid, block, 0, stream,
                       x, Wih1, Whh1, bih1, bhh1, Wih2, Whh2, bih2, bhh2,
                       Wout, bout, outp);
}

// Round 9
// 2573.649 us; speedup vs baseline: 1.0520x; 1.0115x over previous
//
#include <hip/hip_runtime.h>

#define HH   51
#define H4   204
#define TSEQ 2048
#define FUT  64
#define TT   (TSEQ + FUT)   // 2112
#define RPB  16             // batch rows per block (2 blocks/CU)
#define NTH  1024           // 16 waves: 13 compute + emit + prefetch + 1 idle (proven 2-block packing)
#define HSTR 72             // halfs per hbuf row (144 B stride)

typedef _Float16 h8 __attribute__((ext_vector_type(8)));
typedef float    f4 __attribute__((ext_vector_type(4)));

#define LOG2E 1.44269504f
#define MFMA(a, b, c) __builtin_amdgcn_mfma_f32_16x16x32_f16(a, b, c, 0, 0, 0)

// Single-cell activation (peel/tail only). 7 trans. Pre-scaled preacts:
//   g[0]=-L*zi, g[1]=-L*zf, g[2]=-2L*zg, g[3]=-L*zo  (L = log2 e)
__device__ __forceinline__ void act6(const f4 g, float cin, float* cout, float* hout) {
    const float ei = __builtin_amdgcn_exp2f(g[0]);
    const float ef = __builtin_amdgcn_exp2f(g[1]);
    const float eg = __builtin_amdgcn_exp2f(g[2]);
    const float eo = __builtin_amdgcn_exp2f(g[3]);
    const float A = 1.0f + ei, B = 1.0f + ef, G = 1.0f + eg, C = 1.0f + eo;
    const float AB = A * B, GC = G * C;
    const float r  = __builtin_amdgcn_rcpf(AB * GC);
    const float t1 = A * GC;                      // -> f = r*t1
    const float t4 = (B * C) * (2.0f - G);        // -> i*tanh(g) = r*t4
    const float c2 = r * __builtin_fmaf(t1, cin, t4);
    const float og = r * (AB * G);                // sigmoid(zo)
    const float ec = __builtin_amdgcn_exp2f(-2.0f * LOG2E * c2);
    const float th = __builtin_fmaf(2.0f, __builtin_amdgcn_rcpf(1.0f + ec), -1.0f);
    *cout = c2;
    *hout = og * th;
}

// DUAL-cell fused activation: P1 (recurrence) + P2 (emit), both reading the
// same cin. 12 trans (10 exp2 + 2 rcp) vs 14 for two act6 calls:
//   - ONE rcp(P1g*P2g) serves both cells' gate recovery
//     (per-cell ABGC <= e^41, product <= e^82 < f32 max)
//   - ONE rcp(D1*D2) serves both tanh(c)'s (|c| small here)
__device__ __forceinline__ void act_dual(const f4 g1, const f4 g2, float cin,
                                         float* c1n, float* h1v, float* h2v) {
    const float e1i = __builtin_amdgcn_exp2f(g1[0]);
    const float e1f = __builtin_amdgcn_exp2f(g1[1]);
    const float e1g = __builtin_amdgcn_exp2f(g1[2]);
    const float e1o = __builtin_amdgcn_exp2f(g1[3]);
    const float e2i = __builtin_amdgcn_exp2f(g2[0]);
    const float e2f = __builtin_amdgcn_exp2f(g2[1]);
    const float e2g = __builtin_amdgcn_exp2f(g2[2]);
    const float e2o = __builtin_amdgcn_exp2f(g2[3]);
    const float A1 = 1.0f + e1i, B1 = 1.0f + e1f, Gg1 = 1.0f + e1g, C1 = 1.0f + e1o;
    const float A2 = 1.0f + e2i, B2 = 1.0f + e2f, Gg2 = 1.0f + e2g, C2 = 1.0f + e2o;
    const float AB1 = A1 * B1, GC1 = Gg1 * C1, Pa = AB1 * GC1;
    const float AB2 = A2 * B2, GC2 = Gg2 * C2, Pb = AB2 * GC2;
    const float r  = __builtin_amdgcn_rcpf(Pa * Pb);
    const float r1 = r * Pb, r2 = r * Pa;
    // cell 1 (L1 recurrence)
    const float cv1 = r1 * __builtin_fmaf(A1 * GC1, cin, (B1 * C1) * (2.0f - Gg1));
    const float o1  = r1 * (AB1 * Gg1);
    // cell 2 (emit; per reference, also uses cin)
    const float cv2 = r2 * __builtin_fmaf(A2 * GC2, cin, (B2 * C2) * (2.0f - Gg2));
    const float o2  = r2 * (AB2 * Gg2);
    // shared tanh rcp
    const float E1 = __builtin_amdgcn_exp2f(-2.0f * LOG2E * cv1);
    const float E2 = __builtin_amdgcn_exp2f(-2.0f * LOG2E * cv2);
    const float D1 = 1.0f + E1, D2 = 1.0f + E2;
    const float rt = __builtin_amdgcn_rcpf(D1 * D2);
    const float th1 = __builtin_fmaf(2.0f, rt * D2, -1.0f);
    const float th2 = __builtin_fmaf(2.0f, rt * D1, -1.0f);
    *c1n = cv1;
    *h1v = o1 * th1;
    *h2v = o2 * th2;
}

// Merged iteration i (parity P = i&1): P2(i-1) + P1(i), ONE barrier per step
// (R6 skeleton). One ds_read pair feeds all 4 MFMAs; act_dual fuses both
// cells' activations (shared rcps); h1 write issued first (earlier drain).
#define MERGED_BODY(P, EMIT_IDX, DO_EMIT, XI)                                      \
    do {                                                                           \
        if (is_comp) {                                                             \
            const h8 b0 = *(const h8*)&hbuf[P][nl][quad * 8];                      \
            const h8 b1 = *(const h8*)&hbuf[P][nl][32 + quad * 8];                 \
            f4 G1 = {0.f, 0.f, 0.f, 0.f}, G2 = {0.f, 0.f, 0.f, 0.f};               \
            G1 = MFMA(W1[0], b0, G1); G1 = MFMA(W1[1], b1, G1);                    \
            G2 = MFMA(W2[0], b0, G2); G2 = MFMA(W2[1], b1, G2);                    \
            float c1n, h1v, h2v;                                                   \
            act_dual(G1, G2, c1, &c1n, &h1v, &h2v);                                \
            c1 = c1n;                                                              \
            if (kh < HH) hbuf[(P) ^ 1][nl][1 + kh] = (_Float16)h1v;                \
            part[(P) ^ 1][cw][quad][nl] = h2v * wo;                                \
        } else if (w == we) {                                                      \
            if ((DO_EMIT) && lane < RPB) {                                         \
                float s0 = bo, s1 = 0.f, s2 = 0.f, s3 = 0.f;                       \
                _Pragma("unroll")                                                  \
                for (int j = 0; j < 13; ++j) {                                     \
                    s0 += part[P][j][0][lane];                                     \
                    s1 += part[P][j][1][lane];                                     \
                    s2 += part[P][j][2][lane];                                     \
                    s3 += part[P][j][3][lane];                                     \
                }                                                                  \
                out[(size_t)(rb + lane) * TT + (EMIT_IDX)] = (s0 + s1) + (s2 + s3);\
            }                                                                      \
        } else if (w == wp && lane < RPB) {                                        \
            if ((XI) + 1 < TSEQ) hbuf[(P) ^ 1][lane][0] = (_Float16)xnext;         \
            if ((XI) + 2 < TSEQ) xnext = x[(size_t)(rb + lane) * TSEQ + (XI) + 2]; \
        }                                                                          \
        __syncthreads();                                                           \
    } while (0)

__global__ __launch_bounds__(NTH, 8)
void lstm_kernel(const float* __restrict__ x,
                 const float* __restrict__ Wih1, const float* __restrict__ Whh1,
                 const float* __restrict__ bih1, const float* __restrict__ bhh1,
                 const float* __restrict__ Wih2, const float* __restrict__ Whh2,
                 const float* __restrict__ bih2, const float* __restrict__ bhh2,
                 const float* __restrict__ Wout, const float* __restrict__ bout,
                 float* __restrict__ out)
{
    // double-buffered B-operand: [buf][row][k]; k=0: x_t, 1..51: h1, 52,53: const 1 (bias hi/lo)
    __shared__ _Float16 hbuf[2][RPB][HSTR];
    // per-(tile,quad) partials of wout.h2, double-buffered: [buf][tile][quad][row]
    __shared__ float part[2][13][4][17];
    __shared__ float wouts[64];

    const int tid  = threadIdx.x;
    const int lane = tid & 63;
    const int w    = tid >> 6;        // physical wave id (SIMD = w & 3)
    const int quad = lane >> 4;       // 0..3
    const int nl   = lane & 15;       // batch row (B-operand n / C-D col)
    const int rb   = blockIdx.x * RPB;

    // Role rotation: 13 compute waves split 4-3-3-3 over SIMDs; co-resident
    // blocks (b, b+256) use shifts 0 / 3 -> combined 7/6/6/7 per SIMD.
    const int  rot     = (blockIdx.x >> 8) & 1;
    const int  cw      = w - (rot ? 3 : 0);     // compute tile id if in [0,13)
    const bool is_comp = (cw >= 0) && (cw < 13);
    const int  we      = rot ? 0 : 13;          // emit wave
    const int  wp      = rot ? 1 : 14;          // x-prefetch wave

    // ---------------- one-time init ----------------
    if (tid < 64) wouts[tid] = (tid < HH) ? Wout[tid] : 0.0f;
    for (int i = tid; i < 2 * RPB * HSTR; i += NTH) (&hbuf[0][0][0])[i] = (_Float16)0.0f;
    __syncthreads();
    if (tid < RPB) {
        hbuf[0][tid][0]  = (_Float16)x[(size_t)(rb + tid) * TSEQ];
        hbuf[0][tid][52] = (_Float16)1.0f;  hbuf[0][tid][53] = (_Float16)1.0f;
        hbuf[1][tid][52] = (_Float16)1.0f;  hbuf[1][tid][53] = (_Float16)1.0f;
    }
    const float bo = bout[0];

    // ---------------- weight A-fragments in registers (once) ----------------
    // compute wave cw owns gate m-tile cw: rows j' = 16cw..16cw+15 (j' = 4k+q interleave)
    // Gate rows pre-scaled so MFMA emits exp2-ready args: i,f,o by -log2e, g by -2 log2e.
    h8 W1[2], W2[2];
    if (is_comp) {
        const int jp = 16 * cw + nl;
        const int kk = jp >> 2, q = jp & 3;
        const bool valid = (jp < H4);
        const int jrow = q * HH + kk;        // original gate row
        const float sc = (q == 2) ? (-2.0f * LOG2E) : (-LOG2E);
        float b1 = 0.0f, b2 = 0.0f;
        if (valid) { b1 = sc * (bih1[jrow] + bhh1[jrow]); b2 = sc * (bih2[jrow] + bhh2[jrow]); }
        const _Float16 b1h = (_Float16)b1, b2h = (_Float16)b2;
        const _Float16 b1l = (_Float16)(b1 - (float)b1h), b2l = (_Float16)(b2 - (float)b2h);
        #pragma unroll
        for (int s = 0; s < 2; ++s) {
            h8 w1v, w2v;
            #pragma unroll
            for (int j = 0; j < 8; ++j) {
                const int k = s * 32 + quad * 8 + j;
                _Float16 a1 = (_Float16)0.0f, a2 = (_Float16)0.0f;
                if (valid) {
                    if (k == 0) {
                        a1 = (_Float16)(sc * Wih1[jrow]);
                    } else if (k <= HH) {
                        const int o = jrow * HH + (k - 1);
                        a1 = (_Float16)(sc * Whh1[o]);
                        a2 = (_Float16)(sc * (Wih2[o] + Whh2[o]));
                    } else if (k == 52) { a1 = b1h; a2 = b2h; }
                    else if (k == 53)   { a1 = b1l; a2 = b2l; }
                }
                w1v[j] = a1;
                w2v[j] = a2;
            }
            W1[s] = w1v;
            W2[s] = w2v;
        }
    }

    // x register pipeline: at merged iteration i, write x(i+1), then load x(i+2)
    float xnext = 0.0f;
    if (w == wp && lane < RPB) xnext = x[(size_t)(rb + lane) * TSEQ + 1];

    const int kh = 4 * cw + quad;     // hidden unit owned by this lane (if is_comp)
    float c1 = 0.0f;
    __syncthreads();
    const float wo = is_comp ? wouts[kh] : 0.0f;

    // ---------------- peel i = 0 : P1(0) only ----------------
    if (is_comp) {
        const h8 b0 = *(const h8*)&hbuf[0][nl][quad * 8];
        const h8 b1 = *(const h8*)&hbuf[0][nl][32 + quad * 8];
        f4 G1 = {0.f, 0.f, 0.f, 0.f};
        G1 = MFMA(W1[0], b0, G1); G1 = MFMA(W1[1], b1, G1);
        float hv;
        act6(G1, c1, &c1, &hv);
        if (kh < HH) hbuf[1][nl][1 + kh] = (_Float16)hv;
    } else if (w == wp && lane < RPB) {
        hbuf[1][lane][0] = (_Float16)xnext;               // x(1)
        xnext = x[(size_t)(rb + lane) * TSEQ + 2];        // x(2)
    }
    __syncthreads();

    // ---------------- peel i = 1 : P2(0) + P1(1), nothing to emit yet ----------------
    MERGED_BODY(1, 0, false, 1);

    // ---------------- main: merged iterations i = 2 .. TSEQ-1, unrolled x2 ----------------
    for (int i = 2; i < TSEQ; i += 2) {
        MERGED_BODY(0, i - 2, true, i);
        MERGED_BODY(1, i - 1, true, i + 1);
    }
    // state: P1 done through 2047, P2 done through 2046,
    // out emitted through 2045; part[0] holds P2(2046).

    // ---------------- FUT tail: t = TSEQ-1 .. TT-1, explicit 3-phase ----------------
    for (int t = TSEQ - 1; t < TT; ++t) {
        const int pb = (t + 1) & 1;   // buffer holding h1 post-step-t (+ feedback x slot)
        if (is_comp) {
            // P2(t)
            const h8 b0 = *(const h8*)&hbuf[pb][nl][quad * 8];
            const h8 b1 = *(const h8*)&hbuf[pb][nl][32 + quad * 8];
            f4 G2 = {0.f, 0.f, 0.f, 0.f};
            G2 = MFMA(W2[0], b0, G2); G2 = MFMA(W2[1], b1, G2);
            float c2v, h2v;
            act6(G2, c1, &c2v, &h2v);
            part[t & 1][cw][quad][nl] = h2v * wo;
        } else if (w == we && t == TSEQ - 1 && lane < RPB) {
            // emit out(TSEQ-2) from part[0] (written during the last main iter)
            float s0 = bo, s1 = 0.f, s2 = 0.f, s3 = 0.f;
            #pragma unroll
            for (int j = 0; j < 13; ++j) {
                s0 += part[0][j][0][lane];
                s1 += part[0][j][1][lane];
                s2 += part[0][j][2][lane];
                s3 += part[0][j][3][lane];
            }
            out[(size_t)(rb + lane) * TT + (TSEQ - 2)] = (s0 + s1) + (s2 + s3);
        }
        __syncthreads();
        if (w == we && lane < RPB) {
            float s0 = bo, s1 = 0.f, s2 = 0.f, s3 = 0.f;
            #pragma unroll
            for (int j = 0; j < 13; ++j) {
                s0 += part[t & 1][j][0][lane];
                s1 += part[t & 1][j][1][lane];
                s2 += part[t & 1][j][2][lane];
                s3 += part[t & 1][j][3][lane];
            }
            const float s = (s0 + s1) + (s2 + s3);
            out[(size_t)(rb + lane) * TT + t] = s;
            if (t + 1 < TT) hbuf[pb][lane][0] = (_Float16)s;   // autoregressive x(t+1)
        }
        __syncthreads();
        if (t + 1 < TT) {
            if (is_comp) {
                // P1(t+1): reads hbuf[pb] (h1 post-t + feedback x), writes h1 post-(t+1)
                const h8 b0 = *(const h8*)&hbuf[pb][nl][quad * 8];
                const h8 b1 = *(const h8*)&hbuf[pb][nl][32 + quad * 8];
                f4 G1 = {0.f, 0.f, 0.f, 0.f};
                G1 = MFMA(W1[0], b0, G1); G1 = MFMA(W1[1], b1, G1);
                float hv;
                act6(G1, c1, &c1, &hv);
                if (kh < HH) hbuf[pb ^ 1][nl][1 + kh] = (_Float16)hv;
            }
            __syncthreads();
        }
    }
}

extern "C" void kernel_launch(void* const* d_in, const int* in_sizes, int n_in,
                              void* d_out, int out_size, void* d_ws, size_t ws_size,
                              hipStream_t stream) {
    (void)in_sizes; (void)n_in; (void)d_ws; (void)ws_size; (void)out_size;
    const float* x    = (const float*)d_in[0];
    const float* Wih1 = (const float*)d_in[1];
    const float* Whh1 = (const float*)d_in[2];
    const float* bih1 = (const float*)d_in[3];
    const float* bhh1 = (const float*)d_in[4];
    const float* Wih2 = (const float*)d_in[5];
    const float* Whh2 = (const float*)d_in[6];
    const float* bih2 = (const float*)d_in[7];
    const float* bhh2 = (const float*)d_in[8];
    const float* Wout = (const float*)d_in[9];
    const float* bout = (const float*)d_in[10];
    float* outp = (float*)d_out;

    dim3 grid(8192 / RPB);   // 512 blocks, 2 per CU
    dim3 block(NTH);
    hipLaunchKernelGGL(lstm_kernel, grid, block, 0, stream,
                       x, Wih1, Whh1, bih1, bhh1, Wih2, Whh2, bih2, bhh2,
                       Wout, bout, outp);
}